// Round 8
// baseline (122.933 us; speedup 1.0000x reference)
//
#include <hip/hip_runtime.h>
#include <stdint.h>

#define L_DIM 1024
#define N_DIM 64
#define D_DIM 64
#define O_DIM 1024
#define ND    4096              // slice stride (floats) for x / upfold rows
#define NT    8                 // O tiles per team (fallback kernel)

typedef float    floatx16 __attribute__((ext_vector_type(16)));
typedef _Float16 half8    __attribute__((ext_vector_type(8)));
typedef _Float16 h2       __attribute__((ext_vector_type(2)));
typedef __fp16   fp16x2   __attribute__((ext_vector_type(2)));

// ---------- pre-converted U image (r5-verified layout) ----------
// [ Ub: 64 rows x 72 halves (144 B rows)                        = 9216 B ]
// [ UtT: 64 d-rows x 38 u32 (152 B rows; cols = o-pair packed)  = 9728 B ]
#define UB_BYTES  9216
#define UTT_BYTES 9728
#define IMG_BYTES (UB_BYTES + UTT_BYTES)          // 18944
#define WS_NEEDED ((size_t)N_DIM * 16 * IMG_BYTES)

#define BUF_STRIDE_FB 17920     // fallback kernel: Ub 9216 B + Ut2 8704 B

__device__ __forceinline__ uint32_t pkh2(float a, float b) {
    fp16x2 p = __builtin_amdgcn_cvt_pkrtz(a, b);   // v_cvt_pkrtz_f16_f32
    return __builtin_bit_cast(uint32_t, p);
}

__device__ __forceinline__ half8 mk_frag(uint32_t a, uint32_t b, uint32_t c, uint32_t d) {
    union { uint32_t u[4]; half8 v; } U;
    U.u[0] = a; U.u[1] = b; U.u[2] = c; U.u[3] = d;
    return U.v;
}

// sigmoid(s/8) - 0.5 = 0.5*tanh(s/16), odd poly in v=(s/16)^2, packed fp16.
__device__ __forceinline__ uint32_t psig(float s0, float s1) {
    const h2 HI = {(_Float16)41.6f,        (_Float16)41.6f};
    const h2 LO = {(_Float16)-41.6f,       (_Float16)-41.6f};
    const h2 SC = {(_Float16)0.0625f,      (_Float16)0.0625f};
    const h2 C0 = {(_Float16)0.03099238f,  (_Float16)0.03099238f};
    const h2 C1 = {(_Float16)-0.00842090f, (_Float16)-0.00842090f};
    const h2 C2 = {(_Float16)0.00151845f,  (_Float16)0.00151845f};
    const h2 C3 = {(_Float16)-1.02197e-4f, (_Float16)-1.02197e-4f};
    h2 s = __builtin_bit_cast(h2, pkh2(s0, s1));
    s = __builtin_elementwise_min(s, HI);
    s = __builtin_elementwise_max(s, LO);
    h2 ha = s * SC;
    h2 v  = ha * ha;
    h2 w  = C2 + v * C3;
    w     = C1 + v * w;
    w     = C0 + v * w;
    h2 f  = s * w;
    return __builtin_bit_cast(uint32_t, f);
}

// Coalesced U tile load: thread (r8, c) takes rows 2*r8+32j (va) and +1 (vb),
// cols 4c..4c+3.
__device__ __forceinline__ void load_tile(const float* ubase, int ot,
                                          int r8, int c, float4* va, float4* vb) {
    const float* pr = ubase + (size_t)(ot * 64 + 2 * r8) * ND + 4 * c;
    #pragma unroll
    for (int j = 0; j < 2; ++j) {
        va[j] = *(const float4*)(pr + (size_t)(32 * j) * ND);
        vb[j] = *(const float4*)(pr + (size_t)(32 * j) * ND + ND);
    }
}

// ================= kernel A: U (f32) -> packed f16 image (r5-verified) =================
__global__ void __launch_bounds__(256)
conv_kernel(const float* __restrict__ up, unsigned char* __restrict__ img)
{
    const int tid = threadIdx.x;
    const int r8  = tid >> 4;            // 0..15
    const int c   = tid & 15;
    const int n   = blockIdx.x;
    const int ot  = blockIdx.y;

    const float* ubase = up + (size_t)n * D_DIM;
    float4 va[2], vb[2];
    load_tile(ubase, ot, r8, c, va, vb);

    unsigned char* tb = img + (size_t)(n * 16 + ot) * IMG_BYTES;
    uint16_t (*Ub)[72]  = (uint16_t (*)[72])tb;
    uint32_t (*UtT)[38] = (uint32_t (*)[38])(tb + UB_BYTES);

    #pragma unroll
    for (int j = 0; j < 2; ++j) {
        *(uint2*)&Ub[2*r8 + 32*j][4*c] =
            make_uint2(pkh2(va[j].x, va[j].y), pkh2(va[j].z, va[j].w));
        *(uint2*)&Ub[2*r8 + 32*j + 1][4*c] =
            make_uint2(pkh2(vb[j].x, vb[j].y), pkh2(vb[j].z, vb[j].w));
        const int op = r8 + 16*j;        // o-pair index
        UtT[4*c + 0][op] = pkh2(va[j].x, vb[j].x);
        UtT[4*c + 1][op] = pkh2(va[j].y, vb[j].y);
        UtT[4*c + 2][op] = pkh2(va[j].z, vb[j].z);
        UtT[4*c + 3][op] = pkh2(va[j].w, vb[j].w);
    }
}

// ====== kernel B: register-direct compute — U frags global->reg, no LDS, no barriers ======
__global__ void __launch_bounds__(512, 4)
corr_kernel_r(const float* __restrict__ x, const unsigned char* __restrict__ img,
              float* __restrict__ out)
{
    __shared__ __align__(16) float Xs[128][68];   // 34816 B: X overlay, then F-combine

    const int tid  = threadIdx.x;        // 0..511
    const int lane = tid & 63;
    const int wid  = tid >> 6;           // 0..7
    const int team = wid >> 2;           // 0 / 1: o-half of each tile
    const int tw   = wid & 3;            // l-wave within team
    const int l31  = lane & 31;
    const int h    = lane >> 5;          // wave half
    const int n    = blockIdx.x;         // same n -> same XCD (bid%8 = n%8)
    const int lb   = blockIdx.y;         // L-tile of 128 rows
    const int lw   = lb * 128 + tw * 32 + l31;    // this lane's l row

    const unsigned char* gimg = img + (size_t)n * 16 * IMG_BYTES;

    // ---- phase 0: X tile (128 rows) -> LDS fp32, build Xf frags ----
    half8 Xf[4];
    {
        const int xr = tid >> 2;                   // row 0..127
        const int xq = tid & 3;                    // quarter-row
        const float* xsrc = x + (size_t)(lb * 128 + xr) * ND + n * D_DIM;
        #pragma unroll
        for (int j = 0; j < 4; ++j) {
            const int f4i = xq * 4 + j;
            *(float4*)&Xs[xr][4 * f4i] = *(const float4*)(xsrc + 4 * f4i);
        }
        __syncthreads();
        const int rl = tw * 32 + l31;
        #pragma unroll
        for (int kk = 0; kk < 4; ++kk) {
            float4 f1 = *(const float4*)&Xs[rl][16 * kk + 8 * h];
            float4 f2 = *(const float4*)&Xs[rl][16 * kk + 8 * h + 4];
            Xf[kk] = mk_frag(pkh2(f1.x, f1.y), pkh2(f1.z, f1.w),
                             pkh2(f2.x, f2.y), pkh2(f2.z, f2.w));
        }
        __syncthreads();   // Xs reads done before epilogue overlay reuse
    }

    floatx16 F0, F1;   // F^T accumulators, d 0..31 / 32..63 (this team's o-half)
    #pragma unroll
    for (int i = 0; i < 16; ++i) { F0[i] = 0.0f; F1[i] = 0.0f; }

    // ---- main loop: 16 tiles, fully wave-independent, zero barriers ----
    for (int ot = 0; ot < 16; ++ot) {
        const unsigned char* tb = gimg + (size_t)ot * IMG_BYTES;

        // GEMM1 A-frags: dwordx4 reads of Ub rows (this team's o-half), L1-broadcast
        const unsigned char* ubp = tb + (size_t)(team * 32 + l31) * 144 + h * 16;
        half8 Ak[4];
        #pragma unroll
        for (int kk = 0; kk < 4; ++kk)
            Ak[kk] = *(const half8*)(ubp + kk * 32);

        // ---- GEMM1: S^T = U[o-half] * X^T   (M=o 32, N=l 32, K=d 64) ----
        floatx16 S;
        #pragma unroll
        for (int i2 = 0; i2 < 16; ++i2) S[i2] = 0.0f;
        #pragma unroll
        for (int kk = 0; kk < 4; ++kk)
            S = __builtin_amdgcn_mfma_f32_32x32x16_f16(Ak[kk], Xf[kk], S, 0, 0, 0);

        // ---- sigmoid weights: packed-fp16 odd polynomial ----
        uint32_t P[8];
        #pragma unroll
        for (int m = 0; m < 8; ++m) P[m] = psig(S[2*m], S[2*m+1]);

        // ---- GEMM2: F^T += U^T[o-half] * W ----
        uint32_t R[4];
        #pragma unroll
        for (int c2 = 0; c2 < 2; ++c2) {
            const int t4 = c2 * 4;
            R[2*c2]   = __shfl_xor(h ? P[t4]     : P[t4 + 2], 32);
            R[2*c2+1] = __shfl_xor(h ? P[t4 + 1] : P[t4 + 3], 32);
        }
        const uint32_t* r0 = (const uint32_t*)(tb + UB_BYTES) + l31 * 38;
        const uint32_t* r1 = r0 + 32 * 38;
        #pragma unroll
        for (int c2 = 0; c2 < 2; ++c2) {
            const int t4 = c2 * 4;
            half8 B = h ? mk_frag(R[2*c2], R[2*c2+1], P[t4 + 2], P[t4 + 3])
                        : mk_frag(P[t4], P[t4 + 1], R[2*c2], R[2*c2+1]);
            // A-frags: d-major UtT rows (global), contiguous o-pairs, team offset
            const int opb = team * 16 + 8 * c2 + 4 * h;
            uint2 q0 = *(const uint2*)(r0 + opb);
            uint2 q1 = *(const uint2*)(r0 + opb + 2);
            uint2 q2 = *(const uint2*)(r1 + opb);
            uint2 q3 = *(const uint2*)(r1 + opb + 2);
            half8 A0 = mk_frag(q0.x, q0.y, q1.x, q1.y);
            half8 A1 = mk_frag(q2.x, q2.y, q3.x, q3.y);
            F0 = __builtin_amdgcn_mfma_f32_32x32x16_f16(A0, B, F0, 0, 0, 0);
            F1 = __builtin_amdgcn_mfma_f32_32x32x16_f16(A1, B, F1, 0, 0, 0);
        }
    }

    // ---- epilogue: combine o-half partials via LDS overlay, then direct store ----
    {
        const int row = tw * 32 + l31;
        if (team == 1) {
            #pragma unroll
            for (int q = 0; q < 4; ++q) {
                float4 a; a.x = F0[4*q]; a.y = F0[4*q+1]; a.z = F0[4*q+2]; a.w = F0[4*q+3];
                *(float4*)&Xs[row][8*q + 4*h] = a;            // d 0..31
                float4 bq; bq.x = F1[4*q]; bq.y = F1[4*q+1]; bq.z = F1[4*q+2]; bq.w = F1[4*q+3];
                *(float4*)&Xs[row][32 + 8*q + 4*h] = bq;      // d 32..63
            }
        }
        __syncthreads();
        if (team == 0) {
            float* op = out + (size_t)lw * ND + n * D_DIM;
            #pragma unroll
            for (int q = 0; q < 4; ++q) {
                float4 t0 = *(const float4*)&Xs[row][8*q + 4*h];
                float4 a; a.x = F0[4*q]   + t0.x; a.y = F0[4*q+1] + t0.y;
                          a.z = F0[4*q+2] + t0.z; a.w = F0[4*q+3] + t0.w;
                *(float4*)(op + 8*q + 4*h) = a;               // d 0..31
                float4 t1 = *(const float4*)&Xs[row][32 + 8*q + 4*h];
                float4 bq; bq.x = F1[4*q]   + t1.x; bq.y = F1[4*q+1] + t1.y;
                           bq.z = F1[4*q+2] + t1.z; bq.w = F1[4*q+3] + t1.w;
                *(float4*)(op + 32 + 8*q + 4*h) = bq;         // d 32..63
            }
        }
    }
}

// ================= fallback (round-3 chassis, verbatim): used if ws too small =================
__global__ void __launch_bounds__(512, 4)
corr_kernel_fb(const float* __restrict__ x, const float* __restrict__ up,
               float* __restrict__ out)
{
    __shared__ __align__(16) unsigned char smem[4 * BUF_STRIDE_FB];

    const int tid  = threadIdx.x;
    const int lane = tid & 63;
    const int wid  = tid >> 6;
    const int team = wid >> 2;
    const int tw   = wid & 3;
    const int l31  = lane & 31;
    const int h    = lane >> 5;
    const int ttid = tid & 255;
    const int r8   = ttid >> 4;
    const int c    = ttid & 15;
    const int n    = blockIdx.x;
    const int lb   = blockIdx.y;
    const int lw   = lb * 128 + tw * 32 + l31;

    const float* ubase = up + (size_t)n * D_DIM;
    const int ob = team * NT;
    unsigned char* tsmem = smem + team * 2 * BUF_STRIDE_FB;

    float4 va[2], vb[2];
    load_tile(ubase, ob + 0, r8, c, va, vb);

    half8 Xf[4];
    {
        float (*Xs)[68] = (float (*)[68])smem;
        const int xr = tid >> 2;
        const int xq = tid & 3;
        const float* xsrc = x + (size_t)(lb * 128 + xr) * ND + n * D_DIM;
        #pragma unroll
        for (int j = 0; j < 4; ++j) {
            const int f4i = xq * 4 + j;
            *(float4*)&Xs[xr][4 * f4i] = *(const float4*)(xsrc + 4 * f4i);
        }
        __syncthreads();
        const int rl = tw * 32 + l31;
        #pragma unroll
        for (int kk = 0; kk < 4; ++kk) {
            float4 f1 = *(const float4*)&Xs[rl][16 * kk + 8 * h];
            float4 f2 = *(const float4*)&Xs[rl][16 * kk + 8 * h + 4];
            Xf[kk] = mk_frag(pkh2(f1.x, f1.y), pkh2(f1.z, f1.w),
                             pkh2(f2.x, f2.y), pkh2(f2.z, f2.w));
        }
        __syncthreads();
    }

    #pragma unroll
    for (int j = 0; j < 2; ++j) {
        uint16_t (*Ub)[72]  = (uint16_t (*)[72])(tsmem);
        uint32_t (*Ut2)[68] = (uint32_t (*)[68])(tsmem + 9216);
        *(uint2*)&Ub[2*r8 + 32*j][4*c] =
            make_uint2(pkh2(va[j].x, va[j].y), pkh2(va[j].z, va[j].w));
        *(uint2*)&Ub[2*r8 + 32*j + 1][4*c] =
            make_uint2(pkh2(vb[j].x, vb[j].y), pkh2(vb[j].z, vb[j].w));
        *(uint4*)&Ut2[r8 + 16*j][4*c] =
            make_uint4(pkh2(va[j].x, vb[j].x), pkh2(va[j].y, vb[j].y),
                       pkh2(va[j].z, vb[j].z), pkh2(va[j].w, vb[j].w));
    }
    load_tile(ubase, ob + 1, r8, c, va, vb);
    __syncthreads();

    floatx16 F0, F1;
    #pragma unroll
    for (int i = 0; i < 16; ++i) { F0[i] = 0.0f; F1[i] = 0.0f; }

    for (int ot = 0; ot < NT; ++ot) {
        const int b = ot & 1;
        uint16_t (*Ub)[72]   = (uint16_t (*)[72])(tsmem + b * BUF_STRIDE_FB);
        const uint32_t* utp  = (const uint32_t*)(tsmem + b * BUF_STRIDE_FB + 9216);
        uint16_t (*Ubn)[72]  = (uint16_t (*)[72])(tsmem + (b ^ 1) * BUF_STRIDE_FB);
        uint32_t (*Ut2n)[68] = (uint32_t (*)[68])(tsmem + (b ^ 1) * BUF_STRIDE_FB + 9216);

        half8 A0k[4], A1k[4];
        #pragma unroll
        for (int kk = 0; kk < 4; ++kk) {
            A0k[kk] = *(const half8*)&Ub[l31][16 * kk + 8 * h];
            A1k[kk] = *(const half8*)&Ub[32 + l31][16 * kk + 8 * h];
        }

        if (ot + 1 < NT) {
            #pragma unroll
            for (int j = 0; j < 2; ++j) {
                *(uint2*)&Ubn[2*r8 + 32*j][4*c] =
                    make_uint2(pkh2(va[j].x, va[j].y), pkh2(va[j].z, va[j].w));
                *(uint2*)&Ubn[2*r8 + 32*j + 1][4*c] =
                    make_uint2(pkh2(vb[j].x, vb[j].y), pkh2(vb[j].z, vb[j].w));
                *(uint4*)&Ut2n[r8 + 16*j][4*c] =
                    make_uint4(pkh2(va[j].x, vb[j].x), pkh2(va[j].y, vb[j].y),
                               pkh2(va[j].z, vb[j].z), pkh2(va[j].w, vb[j].w));
            }
        }
        if (ot + 2 < NT)
            load_tile(ubase, ob + ot + 2, r8, c, va, vb);

        floatx16 S0, S1;
        #pragma unroll
        for (int i = 0; i < 16; ++i) { S0[i] = 0.0f; S1[i] = 0.0f; }
        #pragma unroll
        for (int kk = 0; kk < 4; ++kk) {
            S0 = __builtin_amdgcn_mfma_f32_32x32x16_f16(A0k[kk], Xf[kk], S0, 0, 0, 0);
            S1 = __builtin_amdgcn_mfma_f32_32x32x16_f16(A1k[kk], Xf[kk], S1, 0, 0, 0);
        }

        uint32_t P[16];
        #pragma unroll
        for (int m = 0; m < 8; ++m) P[m]     = psig(S0[2*m], S0[2*m+1]);
        #pragma unroll
        for (int m = 0; m < 8; ++m) P[8 + m] = psig(S1[2*m], S1[2*m+1]);

        uint32_t R[8];
        #pragma unroll
        for (int c2 = 0; c2 < 4; ++c2) {
            const uint32_t* Q = P + (c2 >> 1) * 8;
            const int t4 = (c2 & 1) * 4;
            R[2*c2]   = __shfl_xor(h ? Q[t4]     : Q[t4 + 2], 32);
            R[2*c2+1] = __shfl_xor(h ? Q[t4 + 1] : Q[t4 + 3], 32);
        }
        #pragma unroll
        for (int c2 = 0; c2 < 4; ++c2) {
            const uint32_t* Q = P + (c2 >> 1) * 8;
            const int t4 = (c2 & 1) * 4;
            half8 B = h ? mk_frag(R[2*c2], R[2*c2+1], Q[t4 + 2], Q[t4 + 3])
                        : mk_frag(Q[t4], Q[t4 + 1], R[2*c2], R[2*c2+1]);
            const int opb = 8 * c2 + 4 * h;
            uint32_t a0[4], a1[4];
            #pragma unroll
            for (int k = 0; k < 4; ++k) {
                a0[k] = utp[(opb + k) * 68 + l31];
                a1[k] = utp[(opb + k) * 68 + 32 + l31];
            }
            half8 A0 = mk_frag(a0[0], a0[1], a0[2], a0[3]);
            half8 A1 = mk_frag(a1[0], a1[1], a1[2], a1[3]);
            F0 = __builtin_amdgcn_mfma_f32_32x32x16_f16(A0, B, F0, 0, 0, 0);
            F1 = __builtin_amdgcn_mfma_f32_32x32x16_f16(A1, B, F1, 0, 0, 0);
        }
        __syncthreads();
    }

    {
        float (*Fs)[68] = (float (*)[68])smem;
        const int row = tw * 32 + l31;
        if (team == 1) {
            #pragma unroll
            for (int q = 0; q < 4; ++q) {
                float4 a; a.x = F0[4*q]; a.y = F0[4*q+1]; a.z = F0[4*q+2]; a.w = F0[4*q+3];
                *(float4*)&Fs[row][8*q + 4*h] = a;
                float4 bq; bq.x = F1[4*q]; bq.y = F1[4*q+1]; bq.z = F1[4*q+2]; bq.w = F1[4*q+3];
                *(float4*)&Fs[row][32 + 8*q + 4*h] = bq;
            }
        }
        __syncthreads();
        if (team == 0) {
            float* op = out + (size_t)lw * ND + n * D_DIM;
            #pragma unroll
            for (int q = 0; q < 4; ++q) {
                float4 t0 = *(const float4*)&Fs[row][8*q + 4*h];
                float4 a; a.x = F0[4*q]   + t0.x; a.y = F0[4*q+1] + t0.y;
                          a.z = F0[4*q+2] + t0.z; a.w = F0[4*q+3] + t0.w;
                *(float4*)(op + 8*q + 4*h) = a;
                float4 t1 = *(const float4*)&Fs[row][32 + 8*q + 4*h];
                float4 bq; bq.x = F1[4*q]   + t1.x; bq.y = F1[4*q+1] + t1.y;
                           bq.z = F1[4*q+2] + t1.z; bq.w = F1[4*q+3] + t1.w;
                *(float4*)(op + 32 + 8*q + 4*h) = bq;
            }
        }
    }
}

extern "C" void kernel_launch(void* const* d_in, const int* in_sizes, int n_in,
                              void* d_out, int out_size, void* d_ws, size_t ws_size,
                              hipStream_t stream)
{
    const float* x  = (const float*)d_in[0];
    const float* up = (const float*)d_in[1];
    float* out      = (float*)d_out;

    if (d_ws != nullptr && ws_size >= WS_NEEDED) {
        unsigned char* img = (unsigned char*)d_ws;
        conv_kernel<<<dim3(N_DIM, 16), dim3(256), 0, stream>>>(up, img);
        corr_kernel_r<<<dim3(N_DIM, L_DIM / 128), dim3(512), 0, stream>>>(x, img, out);
    } else {
        corr_kernel_fb<<<dim3(N_DIM, L_DIM / 128), dim3(512), 0, stream>>>(x, up, out);
    }
}

// Round 9
// 111.631 us; speedup vs baseline: 1.1012x; 1.1012x over previous
//
#include <hip/hip_runtime.h>
#include <stdint.h>

#define L_DIM 1024
#define N_DIM 64
#define D_DIM 64
#define O_DIM 1024
#define ND    4096              // slice stride (floats) for x / upfold rows
#define NT    8                 // O tiles per team (fallback kernel)

typedef float    floatx16 __attribute__((ext_vector_type(16)));
typedef _Float16 half8    __attribute__((ext_vector_type(8)));
typedef _Float16 h2       __attribute__((ext_vector_type(2)));
typedef __fp16   fp16x2   __attribute__((ext_vector_type(2)));

// ---------- fragment-order U image: every main-loop load is lane*16 contiguous ----------
// per 64-o tile (16384 B):
//   G1 [team t][kk]          : 2x4 chunks of 1024 B at  t*4096 + kk*1024
//       lane p, 16B = Ub[t*32 + (p&31)][d = 16*kk + 8*(p>>5) .. +8]   (8 f16)
//   G2 [t][c2][r]  (base 8192): 2x2x2 chunks of 1024 B at 8192 + t*4096 + c2*2048 + r*1024
//       lane p, 16B = UtT[r*32 + (p&31)][op = t*16 + 8*c2 + 4*(p>>5) .. +4]  (4 u32 o-pairs)
#define IMG_BYTES 16384
#define WS_NEEDED ((size_t)N_DIM * 16 * IMG_BYTES)   // 16 MiB

#define BUF_STRIDE_FB 17920     // fallback kernel: Ub 9216 B + Ut2 8704 B

__device__ __forceinline__ uint32_t pkh2(float a, float b) {
    fp16x2 p = __builtin_amdgcn_cvt_pkrtz(a, b);   // v_cvt_pkrtz_f16_f32
    return __builtin_bit_cast(uint32_t, p);
}

__device__ __forceinline__ half8 mk_frag(uint32_t a, uint32_t b, uint32_t c, uint32_t d) {
    union { uint32_t u[4]; half8 v; } U;
    U.u[0] = a; U.u[1] = b; U.u[2] = c; U.u[3] = d;
    return U.v;
}

// sigmoid(s/8) - 0.5 = 0.5*tanh(s/16), odd poly in v=(s/16)^2, packed fp16.
__device__ __forceinline__ uint32_t psig(float s0, float s1) {
    const h2 HI = {(_Float16)41.6f,        (_Float16)41.6f};
    const h2 LO = {(_Float16)-41.6f,       (_Float16)-41.6f};
    const h2 SC = {(_Float16)0.0625f,      (_Float16)0.0625f};
    const h2 C0 = {(_Float16)0.03099238f,  (_Float16)0.03099238f};
    const h2 C1 = {(_Float16)-0.00842090f, (_Float16)-0.00842090f};
    const h2 C2 = {(_Float16)0.00151845f,  (_Float16)0.00151845f};
    const h2 C3 = {(_Float16)-1.02197e-4f, (_Float16)-1.02197e-4f};
    h2 s = __builtin_bit_cast(h2, pkh2(s0, s1));
    s = __builtin_elementwise_min(s, HI);
    s = __builtin_elementwise_max(s, LO);
    h2 ha = s * SC;
    h2 v  = ha * ha;
    h2 w  = C2 + v * C3;
    w     = C1 + v * w;
    w     = C0 + v * w;
    h2 f  = s * w;
    return __builtin_bit_cast(uint32_t, f);
}

// Coalesced U tile load: thread (r8, c) takes rows 2*r8+32j (va) and +1 (vb),
// cols 4c..4c+3.
__device__ __forceinline__ void load_tile(const float* ubase, int ot,
                                          int r8, int c, float4* va, float4* vb) {
    const float* pr = ubase + (size_t)(ot * 64 + 2 * r8) * ND + 4 * c;
    #pragma unroll
    for (int j = 0; j < 2; ++j) {
        va[j] = *(const float4*)(pr + (size_t)(32 * j) * ND);
        vb[j] = *(const float4*)(pr + (size_t)(32 * j) * ND + ND);
    }
}

// ================= kernel A: U (f32) -> fragment-order f16 image =================
__global__ void __launch_bounds__(256)
conv_kernel(const float* __restrict__ up, unsigned char* __restrict__ img)
{
    const int tid = threadIdx.x;
    const int r8  = tid >> 4;            // 0..15
    const int c   = tid & 15;
    const int n   = blockIdx.x;
    const int ot  = blockIdx.y;

    const float* ubase = up + (size_t)n * D_DIM;
    float4 va[2], vb[2];
    load_tile(ubase, ot, r8, c, va, vb);

    unsigned char* tb = img + (size_t)(n * 16 + ot) * IMG_BYTES;

    // ---- G1: thread's 4 cols land in chunk (t=j, kk=c>>2), lane=(o&31)+32*hh ----
    const int kk = c >> 2;
    const int hh = (c >> 1) & 1;
    const int co = (c & 1) * 8;          // byte offset of the 4-half group within 16B
    #pragma unroll
    for (int j = 0; j < 2; ++j) {
        const int o0 = 2 * r8 + 32 * j;
        unsigned char* g1 = tb + j * 4096 + kk * 1024 + co;
        *(uint2*)(g1 + ((o0 & 31) + 32 * hh) * 16) =
            make_uint2(pkh2(va[j].x, va[j].y), pkh2(va[j].z, va[j].w));
        *(uint2*)(g1 + (((o0 + 1) & 31) + 32 * hh) * 16) =
            make_uint2(pkh2(vb[j].x, vb[j].y), pkh2(vb[j].z, vb[j].w));
    }

    // ---- G2: thread's o-pair op=r8+16j, slot=op&3, group g=op>>2 -> (t,c2,h) ----
    #pragma unroll
    for (int j = 0; j < 2; ++j) {
        const int op   = r8 + 16 * j;
        const int g    = op >> 2;
        const int slot = op & 3;
        const int t2   = g >> 2;
        const int c22  = (g >> 1) & 1;
        const int h2i  = g & 1;
        const float* pa = (const float*)&va[j];
        const float* pb = (const float*)&vb[j];
        #pragma unroll
        for (int col = 0; col < 4; ++col) {
            const int d   = 4 * c + col;
            const int r   = d >> 5;
            const int lane = (d & 31) + 32 * h2i;
            *(uint32_t*)(tb + 8192 + t2 * 4096 + c22 * 2048 + r * 1024
                         + lane * 16 + slot * 4) = pkh2(pa[col], pb[col]);
        }
    }
}

// ====== kernel B: register-direct compute — ALL loads lane-contiguous dwordx4 ======
__global__ void __launch_bounds__(512, 4)
corr_kernel_c(const float* __restrict__ x, const unsigned char* __restrict__ img,
              float* __restrict__ out)
{
    __shared__ __align__(16) float Xs[128][68];   // 34816 B: X overlay, then F-combine

    const int tid  = threadIdx.x;        // 0..511
    const int lane = tid & 63;
    const int wid  = tid >> 6;           // 0..7
    const int team = wid >> 2;           // 0 / 1: o-half of each tile
    const int tw   = wid & 3;            // l-wave within team
    const int l31  = lane & 31;
    const int h    = lane >> 5;          // wave half
    const int n    = blockIdx.x;         // same n -> same XCD (bid%8 = n%8)
    const int lb   = blockIdx.y;         // L-tile of 128 rows
    const int lw   = lb * 128 + tw * 32 + l31;    // this lane's l row

    const unsigned char* gimg = img + (size_t)n * 16 * IMG_BYTES;

    // ---- phase 0: X tile (128 rows) -> LDS fp32, build Xf frags ----
    half8 Xf[4];
    {
        const int xr = tid >> 2;                   // row 0..127
        const int xq = tid & 3;                    // quarter-row
        const float* xsrc = x + (size_t)(lb * 128 + xr) * ND + n * D_DIM;
        #pragma unroll
        for (int j = 0; j < 4; ++j) {
            const int f4i = xq * 4 + j;
            *(float4*)&Xs[xr][4 * f4i] = *(const float4*)(xsrc + 4 * f4i);
        }
        __syncthreads();
        const int rl = tw * 32 + l31;
        #pragma unroll
        for (int kk = 0; kk < 4; ++kk) {
            float4 f1 = *(const float4*)&Xs[rl][16 * kk + 8 * h];
            float4 f2 = *(const float4*)&Xs[rl][16 * kk + 8 * h + 4];
            Xf[kk] = mk_frag(pkh2(f1.x, f1.y), pkh2(f1.z, f1.w),
                             pkh2(f2.x, f2.y), pkh2(f2.z, f2.w));
        }
        __syncthreads();   // Xs reads done before epilogue overlay reuse
    }

    floatx16 F0, F1;   // F^T accumulators, d 0..31 / 32..63 (this team's o-half)
    #pragma unroll
    for (int i = 0; i < 16; ++i) { F0[i] = 0.0f; F1[i] = 0.0f; }

    // ---- main loop: 16 tiles, wave-independent, zero barriers, coalesced loads ----
    for (int ot = 0; ot < 16; ++ot) {
        const unsigned char* tb = gimg + (size_t)ot * IMG_BYTES;

        // GEMM1 A-frags: 4 lane-contiguous dwordx4 (1 KB/instr, L1-broadcast)
        const unsigned char* g1 = tb + team * 4096 + lane * 16;
        half8 Ak[4];
        #pragma unroll
        for (int kk = 0; kk < 4; ++kk)
            Ak[kk] = *(const half8*)(g1 + kk * 1024);

        // ---- GEMM1: S^T = U[o-half] * X^T   (M=o 32, N=l 32, K=d 64) ----
        floatx16 S;
        #pragma unroll
        for (int i2 = 0; i2 < 16; ++i2) S[i2] = 0.0f;
        #pragma unroll
        for (int kk = 0; kk < 4; ++kk)
            S = __builtin_amdgcn_mfma_f32_32x32x16_f16(Ak[kk], Xf[kk], S, 0, 0, 0);

        // ---- sigmoid weights: packed-fp16 odd polynomial ----
        uint32_t P[8];
        #pragma unroll
        for (int m = 0; m < 8; ++m) P[m] = psig(S[2*m], S[2*m+1]);

        // ---- GEMM2: F^T += U^T[o-half] * W ----
        uint32_t R[4];
        #pragma unroll
        for (int c2 = 0; c2 < 2; ++c2) {
            const int t4 = c2 * 4;
            R[2*c2]   = __shfl_xor(h ? P[t4]     : P[t4 + 2], 32);
            R[2*c2+1] = __shfl_xor(h ? P[t4 + 1] : P[t4 + 3], 32);
        }
        const unsigned char* g2 = tb + 8192 + team * 4096 + lane * 16;
        #pragma unroll
        for (int c2 = 0; c2 < 2; ++c2) {
            const int t4 = c2 * 4;
            half8 B = h ? mk_frag(R[2*c2], R[2*c2+1], P[t4 + 2], P[t4 + 3])
                        : mk_frag(P[t4], P[t4 + 1], R[2*c2], R[2*c2+1]);
            // A-frags: 2 lane-contiguous dwordx4 per c2
            half8 A0 = *(const half8*)(g2 + c2 * 2048);
            half8 A1 = *(const half8*)(g2 + c2 * 2048 + 1024);
            F0 = __builtin_amdgcn_mfma_f32_32x32x16_f16(A0, B, F0, 0, 0, 0);
            F1 = __builtin_amdgcn_mfma_f32_32x32x16_f16(A1, B, F1, 0, 0, 0);
        }
    }

    // ---- epilogue: combine o-half partials via LDS overlay, then direct store ----
    {
        const int row = tw * 32 + l31;
        if (team == 1) {
            #pragma unroll
            for (int q = 0; q < 4; ++q) {
                float4 a; a.x = F0[4*q]; a.y = F0[4*q+1]; a.z = F0[4*q+2]; a.w = F0[4*q+3];
                *(float4*)&Xs[row][8*q + 4*h] = a;            // d 0..31
                float4 bq; bq.x = F1[4*q]; bq.y = F1[4*q+1]; bq.z = F1[4*q+2]; bq.w = F1[4*q+3];
                *(float4*)&Xs[row][32 + 8*q + 4*h] = bq;      // d 32..63
            }
        }
        __syncthreads();
        if (team == 0) {
            float* op = out + (size_t)lw * ND + n * D_DIM;
            #pragma unroll
            for (int q = 0; q < 4; ++q) {
                float4 t0 = *(const float4*)&Xs[row][8*q + 4*h];
                float4 a; a.x = F0[4*q]   + t0.x; a.y = F0[4*q+1] + t0.y;
                          a.z = F0[4*q+2] + t0.z; a.w = F0[4*q+3] + t0.w;
                *(float4*)(op + 8*q + 4*h) = a;               // d 0..31
                float4 t1 = *(const float4*)&Xs[row][32 + 8*q + 4*h];
                float4 bq; bq.x = F1[4*q]   + t1.x; bq.y = F1[4*q+1] + t1.y;
                           bq.z = F1[4*q+2] + t1.z; bq.w = F1[4*q+3] + t1.w;
                *(float4*)(op + 32 + 8*q + 4*h) = bq;         // d 32..63
            }
        }
    }
}

// ================= fallback (round-3 chassis, verbatim): used if ws too small =================
__global__ void __launch_bounds__(512, 4)
corr_kernel_fb(const float* __restrict__ x, const float* __restrict__ up,
               float* __restrict__ out)
{
    __shared__ __align__(16) unsigned char smem[4 * BUF_STRIDE_FB];

    const int tid  = threadIdx.x;
    const int lane = tid & 63;
    const int wid  = tid >> 6;
    const int team = wid >> 2;
    const int tw   = wid & 3;
    const int l31  = lane & 31;
    const int h    = lane >> 5;
    const int ttid = tid & 255;
    const int r8   = ttid >> 4;
    const int c    = ttid & 15;
    const int n    = blockIdx.x;
    const int lb   = blockIdx.y;
    const int lw   = lb * 128 + tw * 32 + l31;

    const float* ubase = up + (size_t)n * D_DIM;
    const int ob = team * NT;
    unsigned char* tsmem = smem + team * 2 * BUF_STRIDE_FB;

    float4 va[2], vb[2];
    load_tile(ubase, ob + 0, r8, c, va, vb);

    half8 Xf[4];
    {
        float (*Xs)[68] = (float (*)[68])smem;
        const int xr = tid >> 2;
        const int xq = tid & 3;
        const float* xsrc = x + (size_t)(lb * 128 + xr) * ND + n * D_DIM;
        #pragma unroll
        for (int j = 0; j < 4; ++j) {
            const int f4i = xq * 4 + j;
            *(float4*)&Xs[xr][4 * f4i] = *(const float4*)(xsrc + 4 * f4i);
        }
        __syncthreads();
        const int rl = tw * 32 + l31;
        #pragma unroll
        for (int kk = 0; kk < 4; ++kk) {
            float4 f1 = *(const float4*)&Xs[rl][16 * kk + 8 * h];
            float4 f2 = *(const float4*)&Xs[rl][16 * kk + 8 * h + 4];
            Xf[kk] = mk_frag(pkh2(f1.x, f1.y), pkh2(f1.z, f1.w),
                             pkh2(f2.x, f2.y), pkh2(f2.z, f2.w));
        }
        __syncthreads();
    }

    #pragma unroll
    for (int j = 0; j < 2; ++j) {
        uint16_t (*Ub)[72]  = (uint16_t (*)[72])(tsmem);
        uint32_t (*Ut2)[68] = (uint32_t (*)[68])(tsmem + 9216);
        *(uint2*)&Ub[2*r8 + 32*j][4*c] =
            make_uint2(pkh2(va[j].x, va[j].y), pkh2(va[j].z, va[j].w));
        *(uint2*)&Ub[2*r8 + 32*j + 1][4*c] =
            make_uint2(pkh2(vb[j].x, vb[j].y), pkh2(vb[j].z, vb[j].w));
        *(uint4*)&Ut2[r8 + 16*j][4*c] =
            make_uint4(pkh2(va[j].x, vb[j].x), pkh2(va[j].y, vb[j].y),
                       pkh2(va[j].z, vb[j].z), pkh2(va[j].w, vb[j].w));
    }
    load_tile(ubase, ob + 1, r8, c, va, vb);
    __syncthreads();

    floatx16 F0, F1;
    #pragma unroll
    for (int i = 0; i < 16; ++i) { F0[i] = 0.0f; F1[i] = 0.0f; }

    for (int ot = 0; ot < NT; ++ot) {
        const int b = ot & 1;
        uint16_t (*Ub)[72]   = (uint16_t (*)[72])(tsmem + b * BUF_STRIDE_FB);
        const uint32_t* utp  = (const uint32_t*)(tsmem + b * BUF_STRIDE_FB + 9216);
        uint16_t (*Ubn)[72]  = (uint16_t (*)[72])(tsmem + (b ^ 1) * BUF_STRIDE_FB);
        uint32_t (*Ut2n)[68] = (uint32_t (*)[68])(tsmem + (b ^ 1) * BUF_STRIDE_FB + 9216);

        half8 A0k[4], A1k[4];
        #pragma unroll
        for (int kk = 0; kk < 4; ++kk) {
            A0k[kk] = *(const half8*)&Ub[l31][16 * kk + 8 * h];
            A1k[kk] = *(const half8*)&Ub[32 + l31][16 * kk + 8 * h];
        }

        if (ot + 1 < NT) {
            #pragma unroll
            for (int j = 0; j < 2; ++j) {
                *(uint2*)&Ubn[2*r8 + 32*j][4*c] =
                    make_uint2(pkh2(va[j].x, va[j].y), pkh2(va[j].z, va[j].w));
                *(uint2*)&Ubn[2*r8 + 32*j + 1][4*c] =
                    make_uint2(pkh2(vb[j].x, vb[j].y), pkh2(vb[j].z, vb[j].w));
                *(uint4*)&Ut2n[r8 + 16*j][4*c] =
                    make_uint4(pkh2(va[j].x, vb[j].x), pkh2(va[j].y, vb[j].y),
                               pkh2(va[j].z, vb[j].z), pkh2(va[j].w, vb[j].w));
            }
        }
        if (ot + 2 < NT)
            load_tile(ubase, ob + ot + 2, r8, c, va, vb);

        floatx16 S0, S1;
        #pragma unroll
        for (int i = 0; i < 16; ++i) { S0[i] = 0.0f; S1[i] = 0.0f; }
        #pragma unroll
        for (int kk = 0; kk < 4; ++kk) {
            S0 = __builtin_amdgcn_mfma_f32_32x32x16_f16(A0k[kk], Xf[kk], S0, 0, 0, 0);
            S1 = __builtin_amdgcn_mfma_f32_32x32x16_f16(A1k[kk], Xf[kk], S1, 0, 0, 0);
        }

        uint32_t P[16];
        #pragma unroll
        for (int m = 0; m < 8; ++m) P[m]     = psig(S0[2*m], S0[2*m+1]);
        #pragma unroll
        for (int m = 0; m < 8; ++m) P[8 + m] = psig(S1[2*m], S1[2*m+1]);

        uint32_t R[8];
        #pragma unroll
        for (int c2 = 0; c2 < 4; ++c2) {
            const uint32_t* Q = P + (c2 >> 1) * 8;
            const int t4 = (c2 & 1) * 4;
            R[2*c2]   = __shfl_xor(h ? Q[t4]     : Q[t4 + 2], 32);
            R[2*c2+1] = __shfl_xor(h ? Q[t4 + 1] : Q[t4 + 3], 32);
        }
        #pragma unroll
        for (int c2 = 0; c2 < 4; ++c2) {
            const uint32_t* Q = P + (c2 >> 1) * 8;
            const int t4 = (c2 & 1) * 4;
            half8 B = h ? mk_frag(R[2*c2], R[2*c2+1], Q[t4 + 2], Q[t4 + 3])
                        : mk_frag(Q[t4], Q[t4 + 1], R[2*c2], R[2*c2+1]);
            const int opb = 8 * c2 + 4 * h;
            uint32_t a0[4], a1[4];
            #pragma unroll
            for (int k = 0; k < 4; ++k) {
                a0[k] = utp[(opb + k) * 68 + l31];
                a1[k] = utp[(opb + k) * 68 + 32 + l31];
            }
            half8 A0 = mk_frag(a0[0], a0[1], a0[2], a0[3]);
            half8 A1 = mk_frag(a1[0], a1[1], a1[2], a1[3]);
            F0 = __builtin_amdgcn_mfma_f32_32x32x16_f16(A0, B, F0, 0, 0, 0);
            F1 = __builtin_amdgcn_mfma_f32_32x32x16_f16(A1, B, F1, 0, 0, 0);
        }
        __syncthreads();
    }

    {
        float (*Fs)[68] = (float (*)[68])smem;
        const int row = tw * 32 + l31;
        if (team == 1) {
            #pragma unroll
            for (int q = 0; q < 4; ++q) {
                float4 a; a.x = F0[4*q]; a.y = F0[4*q+1]; a.z = F0[4*q+2]; a.w = F0[4*q+3];
                *(float4*)&Fs[row][8*q + 4*h] = a;
                float4 bq; bq.x = F1[4*q]; bq.y = F1[4*q+1]; bq.z = F1[4*q+2]; bq.w = F1[4*q+3];
                *(float4*)&Fs[row][32 + 8*q + 4*h] = bq;
            }
        }
        __syncthreads();
        if (team == 0) {
            float* op = out + (size_t)lw * ND + n * D_DIM;
            #pragma unroll
            for (int q = 0; q < 4; ++q) {
                float4 t0 = *(const float4*)&Fs[row][8*q + 4*h];
                float4 a; a.x = F0[4*q]   + t0.x; a.y = F0[4*q+1] + t0.y;
                          a.z = F0[4*q+2] + t0.z; a.w = F0[4*q+3] + t0.w;
                *(float4*)(op + 8*q + 4*h) = a;
                float4 t1 = *(const float4*)&Fs[row][32 + 8*q + 4*h];
                float4 bq; bq.x = F1[4*q]   + t1.x; bq.y = F1[4*q+1] + t1.y;
                           bq.z = F1[4*q+2] + t1.z; bq.w = F1[4*q+3] + t1.w;
                *(float4*)(op + 32 + 8*q + 4*h) = bq;
            }
        }
    }
}

extern "C" void kernel_launch(void* const* d_in, const int* in_sizes, int n_in,
                              void* d_out, int out_size, void* d_ws, size_t ws_size,
                              hipStream_t stream)
{
    const float* x  = (const float*)d_in[0];
    const float* up = (const float*)d_in[1];
    float* out      = (float*)d_out;

    if (d_ws != nullptr && ws_size >= WS_NEEDED) {
        unsigned char* img = (unsigned char*)d_ws;
        conv_kernel<<<dim3(N_DIM, 16), dim3(256), 0, stream>>>(up, img);
        corr_kernel_c<<<dim3(N_DIM, L_DIM / 128), dim3(512), 0, stream>>>(x, img, out);
    } else {
        corr_kernel_fb<<<dim3(N_DIM, L_DIM / 128), dim3(512), 0, stream>>>(x, up, out);
    }
}

// Round 10
// 108.890 us; speedup vs baseline: 1.1290x; 1.0252x over previous
//
#include <hip/hip_runtime.h>
#include <stdint.h>

#define L_DIM 1024
#define N_DIM 64
#define D_DIM 64
#define O_DIM 1024
#define ND    4096              // slice stride (floats) for x / upfold rows
#define NT    8                 // O tiles per team (fallback kernel)

typedef float    floatx16 __attribute__((ext_vector_type(16)));
typedef _Float16 half8    __attribute__((ext_vector_type(8)));
typedef _Float16 h2       __attribute__((ext_vector_type(2)));
typedef __fp16   fp16x2   __attribute__((ext_vector_type(2)));

// ---------- fragment-order U image (r9-verified layout) ----------
// per 64-o tile (16384 B):
//   G1 [team t][kk]          : 2x4 chunks of 1024 B at  t*4096 + kk*1024
//       lane p, 16B = Ub[t*32 + (p&31)][d = 16*kk + 8*(p>>5) .. +8]   (8 f16)
//   G2 [t][c2][r]  (base 8192): 2x2x2 chunks of 1024 B at 8192 + t*4096 + c2*2048 + r*1024
//       lane p, 16B = UtT[r*32 + (p&31)][op = t*16 + 8*c2 + 4*(p>>5) .. +4]  (4 u32 o-pairs)
#define IMG_BYTES 16384
#define WS_NEEDED ((size_t)N_DIM * 16 * IMG_BYTES)   // 16 MiB

#define BUF_STRIDE_FB 17920     // fallback kernel: Ub 9216 B + Ut2 8704 B

__device__ __forceinline__ uint32_t pkh2(float a, float b) {
    fp16x2 p = __builtin_amdgcn_cvt_pkrtz(a, b);   // v_cvt_pkrtz_f16_f32
    return __builtin_bit_cast(uint32_t, p);
}

__device__ __forceinline__ half8 mk_frag(uint32_t a, uint32_t b, uint32_t c, uint32_t d) {
    union { uint32_t u[4]; half8 v; } U;
    U.u[0] = a; U.u[1] = b; U.u[2] = c; U.u[3] = d;
    return U.v;
}

// sigmoid(s/8) - 0.5 = 0.5*tanh(s/16), odd poly in v=(s/16)^2, packed fp16.
__device__ __forceinline__ uint32_t psig(float s0, float s1) {
    const h2 HI = {(_Float16)41.6f,        (_Float16)41.6f};
    const h2 LO = {(_Float16)-41.6f,       (_Float16)-41.6f};
    const h2 SC = {(_Float16)0.0625f,      (_Float16)0.0625f};
    const h2 C0 = {(_Float16)0.03099238f,  (_Float16)0.03099238f};
    const h2 C1 = {(_Float16)-0.00842090f, (_Float16)-0.00842090f};
    const h2 C2 = {(_Float16)0.00151845f,  (_Float16)0.00151845f};
    const h2 C3 = {(_Float16)-1.02197e-4f, (_Float16)-1.02197e-4f};
    h2 s = __builtin_bit_cast(h2, pkh2(s0, s1));
    s = __builtin_elementwise_min(s, HI);
    s = __builtin_elementwise_max(s, LO);
    h2 ha = s * SC;
    h2 v  = ha * ha;
    h2 w  = C2 + v * C3;
    w     = C1 + v * w;
    w     = C0 + v * w;
    h2 f  = s * w;
    return __builtin_bit_cast(uint32_t, f);
}

// Coalesced U tile load for conv: thread (r8, c) takes rows 2*r8+32j (va)/+1 (vb).
__device__ __forceinline__ void load_tile(const float* ubase, int ot,
                                          int r8, int c, float4* va, float4* vb) {
    const float* pr = ubase + (size_t)(ot * 64 + 2 * r8) * ND + 4 * c;
    #pragma unroll
    for (int j = 0; j < 2; ++j) {
        va[j] = *(const float4*)(pr + (size_t)(32 * j) * ND);
        vb[j] = *(const float4*)(pr + (size_t)(32 * j) * ND + ND);
    }
}

// ================= kernel A: U (f32) -> fragment-order f16 image (r9-verified) =================
__global__ void __launch_bounds__(256)
conv_kernel(const float* __restrict__ up, unsigned char* __restrict__ img)
{
    const int tid = threadIdx.x;
    const int r8  = tid >> 4;            // 0..15
    const int c   = tid & 15;
    const int n   = blockIdx.x;
    const int ot  = blockIdx.y;

    const float* ubase = up + (size_t)n * D_DIM;
    float4 va[2], vb[2];
    load_tile(ubase, ot, r8, c, va, vb);

    unsigned char* tb = img + (size_t)(n * 16 + ot) * IMG_BYTES;

    // ---- G1 ----
    const int kk = c >> 2;
    const int hh = (c >> 1) & 1;
    const int co = (c & 1) * 8;
    #pragma unroll
    for (int j = 0; j < 2; ++j) {
        const int o0 = 2 * r8 + 32 * j;
        unsigned char* g1 = tb + j * 4096 + kk * 1024 + co;
        *(uint2*)(g1 + ((o0 & 31) + 32 * hh) * 16) =
            make_uint2(pkh2(va[j].x, va[j].y), pkh2(va[j].z, va[j].w));
        *(uint2*)(g1 + (((o0 + 1) & 31) + 32 * hh) * 16) =
            make_uint2(pkh2(vb[j].x, vb[j].y), pkh2(vb[j].z, vb[j].w));
    }

    // ---- G2 ----
    #pragma unroll
    for (int j = 0; j < 2; ++j) {
        const int op   = r8 + 16 * j;
        const int g    = op >> 2;
        const int slot = op & 3;
        const int t2   = g >> 2;
        const int c22  = (g >> 1) & 1;
        const int h2i  = g & 1;
        const float* pa = (const float*)&va[j];
        const float* pb = (const float*)&vb[j];
        #pragma unroll
        for (int col = 0; col < 4; ++col) {
            const int d    = 4 * c + col;
            const int r    = d >> 5;
            const int lane = (d & 31) + 32 * h2i;
            *(uint32_t*)(tb + 8192 + t2 * 4096 + c22 * 2048 + r * 1024
                         + lane * 16 + slot * 4) = pkh2(pa[col], pb[col]);
        }
    }
}

// ---- per-tile fragment loads: 8 lane-contiguous dwordx4 ----
__device__ __forceinline__ void load_frags(const unsigned char* tb, int team, int lane,
                                           half8* Ak, half8* G2) {
    const unsigned char* g1 = tb + team * 4096 + (size_t)lane * 16;
    #pragma unroll
    for (int kk = 0; kk < 4; ++kk)
        Ak[kk] = *(const half8*)(g1 + kk * 1024);
    const unsigned char* g2 = tb + 8192 + team * 4096 + (size_t)lane * 16;
    #pragma unroll
    for (int i = 0; i < 4; ++i)
        G2[i] = *(const half8*)(g2 + i * 1024);   // [0]=A0c0 [1]=A1c0 [2]=A0c1 [3]=A1c1
}

// ---- per-tile compute: both l-halves share the U fragments ----
__device__ __forceinline__ void compute_tile(const half8* Ak, const half8* G2,
                                             const half8* Xf0, const half8* Xf1, int h,
                                             floatx16& F00, floatx16& F01,
                                             floatx16& F10, floatx16& F11)
{
    floatx16 S0, S1;
    #pragma unroll
    for (int i = 0; i < 16; ++i) { S0[i] = 0.0f; S1[i] = 0.0f; }
    #pragma unroll
    for (int kk = 0; kk < 4; ++kk) {
        S0 = __builtin_amdgcn_mfma_f32_32x32x16_f16(Ak[kk], Xf0[kk], S0, 0, 0, 0);
        S1 = __builtin_amdgcn_mfma_f32_32x32x16_f16(Ak[kk], Xf1[kk], S1, 0, 0, 0);
    }

    uint32_t P0[8], P1[8];
    #pragma unroll
    for (int m = 0; m < 8; ++m) { P0[m] = psig(S0[2*m], S0[2*m+1]);
                                  P1[m] = psig(S1[2*m], S1[2*m+1]); }

    uint32_t R0[4], R1[4];
    #pragma unroll
    for (int c2 = 0; c2 < 2; ++c2) {
        const int t4 = c2 * 4;
        R0[2*c2]   = __shfl_xor(h ? P0[t4]     : P0[t4 + 2], 32);
        R0[2*c2+1] = __shfl_xor(h ? P0[t4 + 1] : P0[t4 + 3], 32);
        R1[2*c2]   = __shfl_xor(h ? P1[t4]     : P1[t4 + 2], 32);
        R1[2*c2+1] = __shfl_xor(h ? P1[t4 + 1] : P1[t4 + 3], 32);
    }
    #pragma unroll
    for (int c2 = 0; c2 < 2; ++c2) {
        const int t4 = c2 * 4;
        half8 B0 = h ? mk_frag(R0[2*c2], R0[2*c2+1], P0[t4 + 2], P0[t4 + 3])
                     : mk_frag(P0[t4], P0[t4 + 1], R0[2*c2], R0[2*c2+1]);
        half8 B1 = h ? mk_frag(R1[2*c2], R1[2*c2+1], P1[t4 + 2], P1[t4 + 3])
                     : mk_frag(P1[t4], P1[t4 + 1], R1[2*c2], R1[2*c2+1]);
        F00 = __builtin_amdgcn_mfma_f32_32x32x16_f16(G2[2*c2],     B0, F00, 0, 0, 0);
        F01 = __builtin_amdgcn_mfma_f32_32x32x16_f16(G2[2*c2 + 1], B0, F01, 0, 0, 0);
        F10 = __builtin_amdgcn_mfma_f32_32x32x16_f16(G2[2*c2],     B1, F10, 0, 0, 0);
        F11 = __builtin_amdgcn_mfma_f32_32x32x16_f16(G2[2*c2 + 1], B1, F11, 0, 0, 0);
    }
}

// ====== kernel B: 64 l-rows/wave (2x U-fragment reuse) + even/odd register prefetch ======
__global__ void __launch_bounds__(512, 2)
corr_kernel_w(const float* __restrict__ x, const unsigned char* __restrict__ img,
              float* __restrict__ out)
{
    __shared__ __align__(16) float Xs[256][68];   // 69632 B: X overlay, then F-combine

    const int tid  = threadIdx.x;        // 0..511
    const int lane = tid & 63;
    const int wid  = tid >> 6;           // 0..7
    const int team = wid >> 2;           // 0 / 1: o-half of each tile
    const int tw   = wid & 3;            // l-group of 64 rows
    const int l31  = lane & 31;
    const int h    = lane >> 5;          // wave half
    const int n    = blockIdx.x;         // same n -> same XCD (bid%8 = n%8)
    const int lb   = blockIdx.y;         // L-tile of 256 rows

    const unsigned char* gimg = img + (size_t)n * 16 * IMG_BYTES;

    // ---- phase 0: X tile (256 rows) -> LDS fp32, build both Xf sets ----
    half8 Xf0[4], Xf1[4];
    {
        const int xr = tid >> 1;                   // row 0..255
        const int xh = tid & 1;
        const float* xsrc = x + (size_t)(lb * 256 + xr) * ND + n * D_DIM;
        #pragma unroll
        for (int j = 0; j < 8; ++j) {
            const int f4i = xh * 8 + j;
            *(float4*)&Xs[xr][4 * f4i] = *(const float4*)(xsrc + 4 * f4i);
        }
        __syncthreads();
        const int rl0 = tw * 64 + l31;
        const int rl1 = rl0 + 32;
        #pragma unroll
        for (int kk = 0; kk < 4; ++kk) {
            float4 f1 = *(const float4*)&Xs[rl0][16 * kk + 8 * h];
            float4 f2 = *(const float4*)&Xs[rl0][16 * kk + 8 * h + 4];
            Xf0[kk] = mk_frag(pkh2(f1.x, f1.y), pkh2(f1.z, f1.w),
                              pkh2(f2.x, f2.y), pkh2(f2.z, f2.w));
            float4 f3 = *(const float4*)&Xs[rl1][16 * kk + 8 * h];
            float4 f4v = *(const float4*)&Xs[rl1][16 * kk + 8 * h + 4];
            Xf1[kk] = mk_frag(pkh2(f3.x, f3.y), pkh2(f3.z, f3.w),
                              pkh2(f4v.x, f4v.y), pkh2(f4v.z, f4v.w));
        }
        __syncthreads();   // Xs reads done before epilogue overlay reuse
    }

    floatx16 F00, F01, F10, F11;   // [lh][d-half] accumulators
    #pragma unroll
    for (int i = 0; i < 16; ++i) { F00[i] = 0.0f; F01[i] = 0.0f;
                                   F10[i] = 0.0f; F11[i] = 0.0f; }

    // ---- main loop: 16 tiles, even/odd register double-buffer, zero barriers ----
    half8 AkE[4], G2E[4], AkO[4], G2O[4];
    load_frags(gimg, team, lane, AkE, G2E);                       // tile 0
    for (int ot = 0; ot < 16; ot += 2) {
        load_frags(gimg + (size_t)(ot + 1) * IMG_BYTES, team, lane, AkO, G2O);
        compute_tile(AkE, G2E, Xf0, Xf1, h, F00, F01, F10, F11);  // tile ot
        if (ot + 2 < 16)
            load_frags(gimg + (size_t)(ot + 2) * IMG_BYTES, team, lane, AkE, G2E);
        compute_tile(AkO, G2O, Xf0, Xf1, h, F00, F01, F10, F11);  // tile ot+1
    }

    // ---- epilogue: team combine via LDS overlay, then direct store ----
    {
        if (team == 1) {
            #pragma unroll
            for (int lh = 0; lh < 2; ++lh) {
                const int row = tw * 64 + lh * 32 + l31;
                const floatx16& A = lh ? F10 : F00;
                const floatx16& Bq = lh ? F11 : F01;
                #pragma unroll
                for (int q = 0; q < 4; ++q) {
                    float4 a; a.x = A[4*q]; a.y = A[4*q+1]; a.z = A[4*q+2]; a.w = A[4*q+3];
                    *(float4*)&Xs[row][8*q + 4*h] = a;            // d 0..31
                    float4 b2; b2.x = Bq[4*q]; b2.y = Bq[4*q+1]; b2.z = Bq[4*q+2]; b2.w = Bq[4*q+3];
                    *(float4*)&Xs[row][32 + 8*q + 4*h] = b2;      // d 32..63
                }
            }
        }
        __syncthreads();
        if (team == 0) {
            #pragma unroll
            for (int lh = 0; lh < 2; ++lh) {
                const int row = tw * 64 + lh * 32 + l31;
                const floatx16& A = lh ? F10 : F00;
                const floatx16& Bq = lh ? F11 : F01;
                float* op = out + (size_t)(lb * 256 + row) * ND + n * D_DIM;
                #pragma unroll
                for (int q = 0; q < 4; ++q) {
                    float4 t0 = *(const float4*)&Xs[row][8*q + 4*h];
                    float4 a; a.x = A[4*q]   + t0.x; a.y = A[4*q+1] + t0.y;
                              a.z = A[4*q+2] + t0.z; a.w = A[4*q+3] + t0.w;
                    *(float4*)(op + 8*q + 4*h) = a;               // d 0..31
                    float4 t1 = *(const float4*)&Xs[row][32 + 8*q + 4*h];
                    float4 b2; b2.x = Bq[4*q]   + t1.x; b2.y = Bq[4*q+1] + t1.y;
                               b2.z = Bq[4*q+2] + t1.z; b2.w = Bq[4*q+3] + t1.w;
                    *(float4*)(op + 32 + 8*q + 4*h) = b2;         // d 32..63
                }
            }
        }
    }
}

// ================= fallback (round-3 chassis, verbatim): used if ws too small =================
__global__ void __launch_bounds__(512, 4)
corr_kernel_fb(const float* __restrict__ x, const float* __restrict__ up,
               float* __restrict__ out)
{
    __shared__ __align__(16) unsigned char smem[4 * BUF_STRIDE_FB];

    const int tid  = threadIdx.x;
    const int lane = tid & 63;
    const int wid  = tid >> 6;
    const int team = wid >> 2;
    const int tw   = wid & 3;
    const int l31  = lane & 31;
    const int h    = lane >> 5;
    const int ttid = tid & 255;
    const int r8   = ttid >> 4;
    const int c    = ttid & 15;
    const int n    = blockIdx.x;
    const int lb   = blockIdx.y;
    const int lw   = lb * 128 + tw * 32 + l31;

    const float* ubase = up + (size_t)n * D_DIM;
    const int ob = team * NT;
    unsigned char* tsmem = smem + team * 2 * BUF_STRIDE_FB;

    float4 va[2], vb[2];
    load_tile(ubase, ob + 0, r8, c, va, vb);

    half8 Xf[4];
    {
        float (*Xs)[68] = (float (*)[68])smem;
        const int xr = tid >> 2;
        const int xq = tid & 3;
        const float* xsrc = x + (size_t)(lb * 128 + xr) * ND + n * D_DIM;
        #pragma unroll
        for (int j = 0; j < 4; ++j) {
            const int f4i = xq * 4 + j;
            *(float4*)&Xs[xr][4 * f4i] = *(const float4*)(xsrc + 4 * f4i);
        }
        __syncthreads();
        const int rl = tw * 32 + l31;
        #pragma unroll
        for (int kk = 0; kk < 4; ++kk) {
            float4 f1 = *(const float4*)&Xs[rl][16 * kk + 8 * h];
            float4 f2 = *(const float4*)&Xs[rl][16 * kk + 8 * h + 4];
            Xf[kk] = mk_frag(pkh2(f1.x, f1.y), pkh2(f1.z, f1.w),
                             pkh2(f2.x, f2.y), pkh2(f2.z, f2.w));
        }
        __syncthreads();
    }

    #pragma unroll
    for (int j = 0; j < 2; ++j) {
        uint16_t (*Ub)[72]  = (uint16_t (*)[72])(tsmem);
        uint32_t (*Ut2)[68] = (uint32_t (*)[68])(tsmem + 9216);
        *(uint2*)&Ub[2*r8 + 32*j][4*c] =
            make_uint2(pkh2(va[j].x, va[j].y), pkh2(va[j].z, va[j].w));
        *(uint2*)&Ub[2*r8 + 32*j + 1][4*c] =
            make_uint2(pkh2(vb[j].x, vb[j].y), pkh2(vb[j].z, vb[j].w));
        *(uint4*)&Ut2[r8 + 16*j][4*c] =
            make_uint4(pkh2(va[j].x, vb[j].x), pkh2(va[j].y, vb[j].y),
                       pkh2(va[j].z, vb[j].z), pkh2(va[j].w, vb[j].w));
    }
    load_tile(ubase, ob + 1, r8, c, va, vb);
    __syncthreads();

    floatx16 F0, F1;
    #pragma unroll
    for (int i = 0; i < 16; ++i) { F0[i] = 0.0f; F1[i] = 0.0f; }

    for (int ot = 0; ot < NT; ++ot) {
        const int b = ot & 1;
        uint16_t (*Ub)[72]   = (uint16_t (*)[72])(tsmem + b * BUF_STRIDE_FB);
        const uint32_t* utp  = (const uint32_t*)(tsmem + b * BUF_STRIDE_FB + 9216);
        uint16_t (*Ubn)[72]  = (uint16_t (*)[72])(tsmem + (b ^ 1) * BUF_STRIDE_FB);
        uint32_t (*Ut2n)[68] = (uint32_t (*)[68])(tsmem + (b ^ 1) * BUF_STRIDE_FB + 9216);

        half8 A0k[4], A1k[4];
        #pragma unroll
        for (int kk = 0; kk < 4; ++kk) {
            A0k[kk] = *(const half8*)&Ub[l31][16 * kk + 8 * h];
            A1k[kk] = *(const half8*)&Ub[32 + l31][16 * kk + 8 * h];
        }

        if (ot + 1 < NT) {
            #pragma unroll
            for (int j = 0; j < 2; ++j) {
                *(uint2*)&Ubn[2*r8 + 32*j][4*c] =
                    make_uint2(pkh2(va[j].x, va[j].y), pkh2(va[j].z, va[j].w));
                *(uint2*)&Ubn[2*r8 + 32*j + 1][4*c] =
                    make_uint2(pkh2(vb[j].x, vb[j].y), pkh2(vb[j].z, vb[j].w));
                *(uint4*)&Ut2n[r8 + 16*j][4*c] =
                    make_uint4(pkh2(va[j].x, vb[j].x), pkh2(va[j].y, vb[j].y),
                               pkh2(va[j].z, vb[j].z), pkh2(va[j].w, vb[j].w));
            }
        }
        if (ot + 2 < NT)
            load_tile(ubase, ob + ot + 2, r8, c, va, vb);

        floatx16 S0, S1;
        #pragma unroll
        for (int i = 0; i < 16; ++i) { S0[i] = 0.0f; S1[i] = 0.0f; }
        #pragma unroll
        for (int kk = 0; kk < 4; ++kk) {
            S0 = __builtin_amdgcn_mfma_f32_32x32x16_f16(A0k[kk], Xf[kk], S0, 0, 0, 0);
            S1 = __builtin_amdgcn_mfma_f32_32x32x16_f16(A1k[kk], Xf[kk], S1, 0, 0, 0);
        }

        uint32_t P[16];
        #pragma unroll
        for (int m = 0; m < 8; ++m) P[m]     = psig(S0[2*m], S0[2*m+1]);
        #pragma unroll
        for (int m = 0; m < 8; ++m) P[8 + m] = psig(S1[2*m], S1[2*m+1]);

        uint32_t R[8];
        #pragma unroll
        for (int c2 = 0; c2 < 4; ++c2) {
            const uint32_t* Q = P + (c2 >> 1) * 8;
            const int t4 = (c2 & 1) * 4;
            R[2*c2]   = __shfl_xor(h ? Q[t4]     : Q[t4 + 2], 32);
            R[2*c2+1] = __shfl_xor(h ? Q[t4 + 1] : Q[t4 + 3], 32);
        }
        #pragma unroll
        for (int c2 = 0; c2 < 4; ++c2) {
            const uint32_t* Q = P + (c2 >> 1) * 8;
            const int t4 = (c2 & 1) * 4;
            half8 B = h ? mk_frag(R[2*c2], R[2*c2+1], Q[t4 + 2], Q[t4 + 3])
                        : mk_frag(Q[t4], Q[t4 + 1], R[2*c2], R[2*c2+1]);
            const int opb = 8 * c2 + 4 * h;
            uint32_t a0[4], a1[4];
            #pragma unroll
            for (int k = 0; k < 4; ++k) {
                a0[k] = utp[(opb + k) * 68 + l31];
                a1[k] = utp[(opb + k) * 68 + 32 + l31];
            }
            half8 A0 = mk_frag(a0[0], a0[1], a0[2], a0[3]);
            half8 A1 = mk_frag(a1[0], a1[1], a1[2], a1[3]);
            F0 = __builtin_amdgcn_mfma_f32_32x32x16_f16(A0, B, F0, 0, 0, 0);
            F1 = __builtin_amdgcn_mfma_f32_32x32x16_f16(A1, B, F1, 0, 0, 0);
        }
        __syncthreads();
    }

    {
        float (*Fs)[68] = (float (*)[68])smem;
        const int row = tw * 32 + l31;
        if (team == 1) {
            #pragma unroll
            for (int q = 0; q < 4; ++q) {
                float4 a; a.x = F0[4*q]; a.y = F0[4*q+1]; a.z = F0[4*q+2]; a.w = F0[4*q+3];
                *(float4*)&Fs[row][8*q + 4*h] = a;
                float4 bq; bq.x = F1[4*q]; bq.y = F1[4*q+1]; bq.z = F1[4*q+2]; bq.w = F1[4*q+3];
                *(float4*)&Fs[row][32 + 8*q + 4*h] = bq;
            }
        }
        __syncthreads();
        if (team == 0) {
            float* op = out + (size_t)lw * ND + n * D_DIM;
            #pragma unroll
            for (int q = 0; q < 4; ++q) {
                float4 t0 = *(const float4*)&Fs[row][8*q + 4*h];
                float4 a; a.x = F0[4*q]   + t0.x; a.y = F0[4*q+1] + t0.y;
                          a.z = F0[4*q+2] + t0.z; a.w = F0[4*q+3] + t0.w;
                *(float4*)(op + 8*q + 4*h) = a;
                float4 t1 = *(const float4*)&Fs[row][32 + 8*q + 4*h];
                float4 bq; bq.x = F1[4*q]   + t1.x; bq.y = F1[4*q+1] + t1.y;
                           bq.z = F1[4*q+2] + t1.z; bq.w = F1[4*q+3] + t1.w;
                *(float4*)(op + 32 + 8*q + 4*h) = bq;
            }
        }
    }
}

extern "C" void kernel_launch(void* const* d_in, const int* in_sizes, int n_in,
                              void* d_out, int out_size, void* d_ws, size_t ws_size,
                              hipStream_t stream)
{
    const float* x  = (const float*)d_in[0];
    const float* up = (const float*)d_in[1];
    float* out      = (float*)d_out;

    if (d_ws != nullptr && ws_size >= WS_NEEDED) {
        unsigned char* img = (unsigned char*)d_ws;
        conv_kernel<<<dim3(N_DIM, 16), dim3(256), 0, stream>>>(up, img);
        corr_kernel_w<<<dim3(N_DIM, L_DIM / 256), dim3(512), 0, stream>>>(x, img, out);
    } else {
        corr_kernel_fb<<<dim3(N_DIM, L_DIM / 128), dim3(512), 0, stream>>>(x, up, out);
    }
}